// Round 6
// baseline (891.912 us; speedup 1.0000x reference)
//
#include <hip/hip_runtime.h>

// ---------------------------------------------------------------------------
// DecoderBlock on MI355X (gfx950).  B=2, L=2048, D=2048, H=16, DH=128, FF=8192
// Round 6: QKV and FF1 GEMMs moved to a 256x256 deep-pipelined kernel
// (BK=32, 4 LDS tile-buffers, counted vmcnt(8), raw s_barrier phases,
// setprio MFMA clusters, source-side T2 swizzle).  WO/FF2 stay on the
// verified 128^2 kernel.  Attention/rope/v_transpose unchanged from R5.
// ---------------------------------------------------------------------------

typedef __bf16 bf16;
typedef __bf16 bf16x8 __attribute__((ext_vector_type(8)));
typedef float  f32x4  __attribute__((ext_vector_type(4)));

__device__ __forceinline__ void gload16(const void* g, void* l) {
  __builtin_amdgcn_global_load_lds((const __attribute__((address_space(1))) void*)g,
                                   (__attribute__((address_space(3))) void*)l,
                                   16, 0, 0);
}

#define CBAR asm volatile("" ::: "memory")

// ------------------------------ RMSNorm (f32 -> bf16) ----------------------
// SWZ: write granule (16B) position (tid&3) ^ (row&3) within each 32-col
// K-block, so a linear global_load_lds stage + slot-XOR read is conflict-free.
template<bool SWZ>
__global__ __launch_bounds__(256) void rmsnorm_to_bf16(
    const float* __restrict__ x, const float* __restrict__ w, bf16* __restrict__ out)
{
  const int D = 2048;
  const int row = blockIdx.x;
  const int tid = threadIdx.x;
  const float* xr = x + (size_t)row * D;
  float4 a = ((const float4*)xr)[tid * 2];
  float4 c = ((const float4*)xr)[tid * 2 + 1];
  float ss = a.x*a.x + a.y*a.y + a.z*a.z + a.w*a.w
           + c.x*c.x + c.y*c.y + c.z*c.z + c.w*c.w;
  #pragma unroll
  for (int m = 1; m < 64; m <<= 1) ss += __shfl_xor(ss, m, 64);
  __shared__ float red[4];
  if ((tid & 63) == 0) red[tid >> 6] = ss;
  __syncthreads();
  float tot = red[0] + red[1] + red[2] + red[3];
  float rms = rsqrtf(tot * (1.0f / D) + 1.1920929e-7f);
  const float* wr = w + tid * 8;
  float vals[8] = {a.x, a.y, a.z, a.w, c.x, c.y, c.z, c.w};
  bf16x8 o;
  #pragma unroll
  for (int j = 0; j < 8; ++j) o[j] = (bf16)(vals[j] * rms * wr[j]);
  const int gp = SWZ ? ((tid & ~3) | ((tid & 3) ^ (row & 3))) : tid;
  *(bf16x8*)(out + (size_t)row * D + gp * 8) = o;
}

// --------------------- transpose + convert f32[R][C] -> bf16[C][R] ---------
// SWZ: within each 32-elem K-block of the output row n, granule g stored at
// g ^ (n&3)  (for the 256^2 GEMM's B operand).
template<bool SWZ>
__global__ __launch_bounds__(256) void transpose_to_bf16(
    const float* __restrict__ in, bf16* __restrict__ out, int R, int C)
{
  __shared__ float tile[32][33];
  const int tx = threadIdx.x, ty = threadIdx.y;      // 32 x 8
  const int c0 = blockIdx.x * 32, r0 = blockIdx.y * 32;
  #pragma unroll
  for (int i = 0; i < 4; ++i)
    tile[ty + i * 8][tx] = in[(size_t)(r0 + ty + i * 8) * C + c0 + tx];
  __syncthreads();
  #pragma unroll
  for (int i = 0; i < 4; ++i) {
    const int n = c0 + ty + i * 8;
    const int r = r0 + tx;
    const int cw = SWZ ? ((r & ~31) | ((((r >> 3) & 3) ^ (n & 3)) << 3) | (r & 7)) : r;
    out[(size_t)n * R + cw] = (bf16)tile[tx][ty + i * 8];
  }
}

// --------------- V[b*L+key][h*128+dh] -> VT[(bh*128+dh)][key'] (bf16) ------
__global__ __launch_bounds__(256) void v_transpose(
    const bf16* __restrict__ v, bf16* __restrict__ vt)
{
  const int L = 2048, DM = 2048;
  __shared__ bf16 tile[32][33];
  const int tx = threadIdx.x, ty = threadIdx.y;      // 32 x 8
  const int k0 = blockIdx.x * 32;
  const int d0 = blockIdx.y * 32;
  const int bh = blockIdx.z;
  const int b = bh >> 4, h = bh & 15;
  #pragma unroll
  for (int i = 0; i < 4; ++i)
    tile[ty + i * 8][tx] = v[(size_t)(b * L + k0 + ty + i * 8) * DM + h * 128 + d0 + tx];
  __syncthreads();
  #pragma unroll
  for (int i = 0; i < 4; ++i) {
    const int d = d0 + ty + i * 8;
    const int key = k0 + tx;
    const int keysw = (key & ~63) | (((((key >> 3) & 7) ^ (d & 7)) << 3)) | (key & 7);
    vt[(size_t)(bh * 128 + d) * L + keysw] = tile[tx][ty + i * 8];
  }
}

// ------------------ 256x256 deep-pipelined GEMM (BK=32) --------------------
// C = A[M,K] * Bt[N,K]^T.  8 waves (512 thr), per-wave C = 128x64.
// 4 LDS tile-buffers, prefetch distance 3, vmcnt(8) once per tile.
// A/Bt sources must be pre-swizzled: granule g of each 32-col K-block of row
// r stored at position g ^ (r&3).
// EPI: 2 = silu bf16 ; 3 = bf16 split q/k/v slabs (N=6144)
template<int EPI>
__global__ __launch_bounds__(512, 1) void gemm256(
    const bf16* __restrict__ A, const bf16* __restrict__ Bt,
    void* Cout, int M, int N, int K)
{
  __shared__ bf16 sA[4][2][128 * 32];   // [buf][half][r*32+c]  64 KB
  __shared__ bf16 sB[4][2][128 * 32];   // 64 KB

  const int tid = threadIdx.x;
  const int lane = tid & 63;
  const int w = tid >> 6;          // 0..7
  const int wm = w >> 2;           // 0..1 : A half / C row-half
  const int wn = w & 3;            // 0..3 : C col quarter (64 cols)
  const int lo = lane & 15, hi = lane >> 4;
  const int sl = hi ^ (lo & 3);    // read slot for original granule hi

  const int nbn = N >> 8;
  const int nwg = gridDim.x;
  const int bid = blockIdx.x;
  int swz = bid;
  if ((nwg & 7) == 0) { const int cpx = nwg >> 3; swz = (bid & 7) * cpx + (bid >> 3); }
  const int bm = swz / nbn, bn = swz % nbn;

  // staging: thread covers row tid>>2, slot tid&3 of each 128x32 half (1 load)
  const int srow = tid >> 2, sslot = tid & 3;
  const bf16* aS0 = A  + (size_t)(bm * 256 + srow) * K + sslot * 8;
  const bf16* aS1 = aS0 + (size_t)128 * K;
  const bf16* bS0 = Bt + (size_t)(bn * 256 + srow) * K + sslot * 8;
  const bf16* bS1 = bS0 + (size_t)128 * K;
  const int wb = w * 512;          // wave's element base in an 8KB half

  f32x4 acc[8][4] = {};
  const int NT = K >> 5;           // >= 4 required

#define STAGE_A(T) { gload16(aS0 + (size_t)(T) * 32, &sA[(T) & 3][0][wb]); \
                     gload16(aS1 + (size_t)(T) * 32, &sA[(T) & 3][1][wb]); }
#define STAGE_B(T) { gload16(bS0 + (size_t)(T) * 32, &sB[(T) & 3][0][wb]); \
                     gload16(bS1 + (size_t)(T) * 32, &sB[(T) & 3][1][wb]); }

  // prologue: tiles 0,1,2 in flight (12 loads); wait tile 0 (<=8 outstanding)
  STAGE_A(0) STAGE_B(0)
  STAGE_A(1) STAGE_B(1)
  STAGE_A(2) STAGE_B(2)
  asm volatile("s_waitcnt vmcnt(8)" ::: "memory");
  CBAR; __builtin_amdgcn_s_barrier(); CBAR;

  // Ledger (per thread, 4 loads/tile): end of iter j waits vmcnt(8) ->
  // outstanding = tiles {j+2, j+3} only => tile j+1 proven landed before
  // iter j+1 reads it.  Tail peels to vmcnt(4) / vmcnt(0) / none.
#define G_ITER(KT, DO_STAGE, WAITOP)                                          \
  {                                                                           \
    const int buf_ = (KT) & 3;                                                \
    bf16x8 bfr[4], afr[4];                                                    \
    if (DO_STAGE) STAGE_A((KT) + 3)                                           \
    _Pragma("unroll")                                                         \
    for (int ni = 0; ni < 4; ++ni)                                            \
      bfr[ni] = *(const bf16x8*)&sB[buf_][wn >> 1][((wn & 1) * 64 + ni * 16 + lo) * 32 + sl * 8]; \
    _Pragma("unroll")                                                         \
    for (int mi = 0; mi < 4; ++mi)                                            \
      afr[mi] = *(const bf16x8*)&sA[buf_][wm][(mi * 16 + lo) * 32 + sl * 8];  \
    CBAR; __builtin_amdgcn_s_barrier(); CBAR;                                 \
    __builtin_amdgcn_s_setprio(1);                                            \
    _Pragma("unroll")                                                         \
    for (int mi = 0; mi < 4; ++mi)                                            \
      _Pragma("unroll")                                                       \
      for (int ni = 0; ni < 4; ++ni)                                          \
        acc[mi][ni] = __builtin_amdgcn_mfma_f32_16x16x32_bf16(afr[mi], bfr[ni], acc[mi][ni], 0, 0, 0); \
    __builtin_amdgcn_s_setprio(0);                                            \
    CBAR; __builtin_amdgcn_s_barrier(); CBAR;                                 \
    if (DO_STAGE) STAGE_B((KT) + 3)                                           \
    _Pragma("unroll")                                                         \
    for (int mi = 0; mi < 4; ++mi)                                            \
      afr[mi] = *(const bf16x8*)&sA[buf_][wm][((mi + 4) * 16 + lo) * 32 + sl * 8]; \
    CBAR; __builtin_amdgcn_s_barrier(); CBAR;                                 \
    __builtin_amdgcn_s_setprio(1);                                            \
    _Pragma("unroll")                                                         \
    for (int mi = 0; mi < 4; ++mi)                                            \
      _Pragma("unroll")                                                       \
      for (int ni = 0; ni < 4; ++ni)                                          \
        acc[mi + 4][ni] = __builtin_amdgcn_mfma_f32_16x16x32_bf16(afr[mi], bfr[ni], acc[mi + 4][ni], 0, 0, 0); \
    __builtin_amdgcn_s_setprio(0);                                            \
    WAITOP;                                                                   \
    CBAR; __builtin_amdgcn_s_barrier(); CBAR;                                 \
  }

  int kt = 0;
  for (; kt + 3 < NT; ++kt)
    G_ITER(kt, true, asm volatile("s_waitcnt vmcnt(8)" ::: "memory"))
  G_ITER(kt, false, asm volatile("s_waitcnt vmcnt(4)" ::: "memory")) ++kt;
  G_ITER(kt, false, asm volatile("s_waitcnt vmcnt(0)" ::: "memory")) ++kt;
  G_ITER(kt, false, CBAR)

#undef G_ITER
#undef STAGE_A
#undef STAGE_B

  // epilogue: row = bm*256 + wm*128 + mi*16 + hi*4 + j ; col = bn*256 + wn*64 + ni*16 + lo
  #pragma unroll
  for (int mi = 0; mi < 8; ++mi) {
    #pragma unroll
    for (int j = 0; j < 4; ++j) {
      const size_t row = (size_t)(bm * 256 + wm * 128 + mi * 16 + hi * 4 + j);
      #pragma unroll
      for (int ni = 0; ni < 4; ++ni) {
        const int col = bn * 256 + wn * 64 + ni * 16 + lo;
        const float v = acc[mi][ni][j];
        if constexpr (EPI == 2) {
          ((bf16*)Cout)[row * (size_t)N + col] = (bf16)(v / (1.0f + __expf(-v)));
        } else {
          ((bf16*)Cout)[(size_t)(col >> 11) * 8388608 + row * 2048 + (col & 2047)] = (bf16)v;
        }
      }
    }
  }
}

// ------------------------------ GEMM 128^2 (verified): C = A * Bt^T --------
// EPI: 1 = f32 out + f32 resid  (used for WO and FF2; linear A/B sources)
template<int EPI>
__global__ __launch_bounds__(256, 2) void gemm_bt(
    const bf16* __restrict__ A, const bf16* __restrict__ Bt,
    void* Cout, const float* resid, int M, int N, int K)
{
  __shared__ bf16 sA[128 * 64];
  __shared__ bf16 sB[128 * 64];

  const int tid = threadIdx.x;
  const int lane = tid & 63;
  const int w = tid >> 6;
  const int wm = w >> 1, wn = w & 1;
  const int lo = lane & 15, hi = lane >> 4;

  const int nbn = N >> 7;
  const int nwg = gridDim.x;
  const int bid = blockIdx.x;
  int swz = bid;
  if ((nwg & 7) == 0) { const int cpx = nwg >> 3; swz = (bid & 7) * cpx + (bid >> 3); }
  const int bm = swz / nbn, bn = swz % nbn;

  const bf16* aptr[4];
  const bf16* bptr[4];
  #pragma unroll
  for (int i = 0; i < 4; ++i) {
    const int g = i * 256 + tid;
    const int row = g >> 3, gr = g & 7;
    aptr[i] = A  + (size_t)(bm * 128 + row) * K + gr * 8;
    bptr[i] = Bt + (size_t)(bn * 128 + row) * K + gr * 8;
  }

  f32x4 acc[4][4] = {};
  const int nkt = K >> 6;
  for (int kt = 0; kt < nkt; ++kt) {
    #pragma unroll
    for (int i = 0; i < 4; ++i) {
      gload16(aptr[i] + kt * 64, &sA[(i * 256 + w * 64) * 8]);
      gload16(bptr[i] + kt * 64, &sB[(i * 256 + w * 64) * 8]);
    }
    __syncthreads();
    #pragma unroll
    for (int ks = 0; ks < 2; ++ks) {
      bf16x8 af[4], bfm[4];
      #pragma unroll
      for (int mi = 0; mi < 4; ++mi)
        af[mi] = *(const bf16x8*)&sA[(wm * 64 + mi * 16 + lo) * 64 + ks * 32 + hi * 8];
      #pragma unroll
      for (int ni = 0; ni < 4; ++ni)
        bfm[ni] = *(const bf16x8*)&sB[(wn * 64 + ni * 16 + lo) * 64 + ks * 32 + hi * 8];
      #pragma unroll
      for (int mi = 0; mi < 4; ++mi)
        #pragma unroll
        for (int ni = 0; ni < 4; ++ni)
          acc[mi][ni] = __builtin_amdgcn_mfma_f32_16x16x32_bf16(af[mi], bfm[ni], acc[mi][ni], 0, 0, 0);
    }
    __syncthreads();
  }

  #pragma unroll
  for (int mi = 0; mi < 4; ++mi) {
    #pragma unroll
    for (int j = 0; j < 4; ++j) {
      const size_t row = (size_t)(bm * 128 + wm * 64 + mi * 16 + hi * 4 + j);
      const size_t ro = row * (size_t)N;
      #pragma unroll
      for (int ni = 0; ni < 4; ++ni) {
        const int col = bn * 128 + wn * 64 + ni * 16 + lo;
        const float v = acc[mi][ni][j];
        ((float*)Cout)[ro + col] = v + resid[ro + col];
      }
    }
  }
}

// ------------------- RoPE: q in-place; k -> kswz with granule swizzle ------
__global__ __launch_bounds__(256) void rope_qk(
    bf16* q, const bf16* __restrict__ k, bf16* __restrict__ kswz,
    const float* __restrict__ cs, const float* __restrict__ sn)
{
  const int L = 2048, DM = 2048;
  const int idx = blockIdx.x * 256 + threadIdx.x;
  const int m = idx >> 7;
  const int rem = idx & 127;
  const int h = rem >> 3, t8 = rem & 7;
  const int pos = m & (L - 1);
  const int d0 = t8 * 8;
  const float* cb = cs + (size_t)pos * 128 + d0;
  const float* sb = sn + (size_t)pos * 128 + d0;
  float4 c1a = *(const float4*)(cb);      float4 c1b = *(const float4*)(cb + 4);
  float4 c2a = *(const float4*)(cb + 64); float4 c2b = *(const float4*)(cb + 68);
  float4 s1a = *(const float4*)(sb);      float4 s1b = *(const float4*)(sb + 4);
  float4 s2a = *(const float4*)(sb + 64); float4 s2b = *(const float4*)(sb + 68);
  float c1[8] = {c1a.x,c1a.y,c1a.z,c1a.w,c1b.x,c1b.y,c1b.z,c1b.w};
  float c2[8] = {c2a.x,c2a.y,c2a.z,c2a.w,c2b.x,c2b.y,c2b.z,c2b.w};
  float s1[8] = {s1a.x,s1a.y,s1a.z,s1a.w,s1b.x,s1b.y,s1b.z,s1b.w};
  float s2[8] = {s2a.x,s2a.y,s2a.z,s2a.w,s2b.x,s2b.y,s2b.z,s2b.w};
  const size_t base = (size_t)m * DM + h * 128 + d0;

  {
    bf16x8 x1 = *(bf16x8*)(q + base);
    bf16x8 x2 = *(bf16x8*)(q + base + 64);
    bf16x8 o1, o2;
    #pragma unroll
    for (int j = 0; j < 8; ++j) {
      const float a = (float)x1[j], b = (float)x2[j];
      o1[j] = (bf16)(a * c1[j] - b * s1[j]);
      o2[j] = (bf16)(b * c2[j] + a * s2[j]);
    }
    *(bf16x8*)(q + base) = o1;
    *(bf16x8*)(q + base + 64) = o2;
  }
  {
    bf16x8 x1 = *(const bf16x8*)(k + base);
    bf16x8 x2 = *(const bf16x8*)(k + base + 64);
    bf16x8 o1, o2;
    #pragma unroll
    for (int j = 0; j < 8; ++j) {
      const float a = (float)x1[j], b = (float)x2[j];
      o1[j] = (bf16)(a * c1[j] - b * s1[j]);
      o2[j] = (bf16)(b * c2[j] + a * s2[j]);
    }
    const int s = pos & 15;
    const int p1 = t8 ^ s;
    const int p2 = (8 + t8) ^ s;
    bf16* kr = kswz + (size_t)m * DM + h * 128;
    *(bf16x8*)(kr + p1 * 8) = o1;
    *(bf16x8*)(kr + p2 * 8) = o2;
  }
}

// ------------------------------ Flash attention (R5, verified) -------------
__global__ __launch_bounds__(256, 2) void attn_fwd(
    const bf16* __restrict__ Q, const bf16* __restrict__ Kswz,
    const bf16* __restrict__ VT, const int* __restrict__ mask,
    bf16* __restrict__ O)
{
  const int L = 2048, DM = 2048;
  __shared__ bf16 Kt[2][64 * 128];
  __shared__ bf16 Vt[2][128 * 64];
  __shared__ bf16 Plds[4][16 * 64];

  const int tid = threadIdx.x, lane = tid & 63, w = tid >> 6;
  const int lo = lane & 15, hi = lane >> 4;
  const int s7 = lo & 7;
  const int n = blockIdx.x;
  const int xcd = n & 7, slot = n >> 3;
  const int bh = xcd + 8 * (slot >> 5);
  const int tile = 31 - (slot & 31);
  const int b = bh >> 4, h = bh & 15;
  const int qrow = tile * 64 + w * 16;
  const float scale = 0.08838834764831845f;
  const float NEG_INF = -__builtin_inff();

  bf16x8 qf[4];
  {
    const bf16* qb = Q + (size_t)(b * L + qrow + lo) * DM + h * 128;
    #pragma unroll
    for (int ds = 0; ds < 4; ++ds) qf[ds] = *(const bf16x8*)(qb + ds * 32 + hi * 8);
  }

  float mrow[4] = {NEG_INF, NEG_INF, NEG_INF, NEG_INF};
  float lrow[4] = {0.f, 0.f, 0.f, 0.f};
  f32x4 oacc[8] = {};

  const bf16* vsrc[4];
  const bf16* ksrc[4];
  #pragma unroll
  for (int i = 0; i < 4; ++i) {
    const int gv = i * 256 + tid;
    vsrc[i] = VT + (size_t)(bh * 128 + (gv >> 3)) * L + (gv & 7) * 8;
    const int gk = i * 256 + tid;
    ksrc[i] = Kswz + (size_t)(b * L + (gk >> 4)) * DM + h * 128 + (gk & 15) * 8;
  }

  #pragma unroll
  for (int i = 0; i < 4; ++i) {
    gload16(ksrc[i], &Kt[0][(i * 256 + w * 64) * 8]);
    gload16(vsrc[i], &Vt[0][(i * 256 + w * 64) * 8]);
  }
  __syncthreads();

  const int nkt = tile + 1;
  for (int kt = 0; kt < nkt; ++kt) {
    const int buf = kt & 1;
    if (kt + 1 < nkt) {
      #pragma unroll
      for (int i = 0; i < 4; ++i) {
        gload16(ksrc[i] + (size_t)(kt + 1) * 64 * DM, &Kt[buf ^ 1][(i * 256 + w * 64) * 8]);
        gload16(vsrc[i] + (kt + 1) * 64,              &Vt[buf ^ 1][(i * 256 + w * 64) * 8]);
      }
    }

    int mk[4];
    #pragma unroll
    for (int kb = 0; kb < 4; ++kb) mk[kb] = mask[b * L + kt * 64 + kb * 16 + lo];

    f32x4 S[4];
    __builtin_amdgcn_s_setprio(1);
    #pragma unroll
    for (int kb = 0; kb < 4; ++kb) {
      f32x4 s = {};
      #pragma unroll
      for (int ds = 0; ds < 4; ++ds) {
        const bf16x8 kf = *(const bf16x8*)&Kt[buf][(kb * 16 + lo) * 128 + (((ds * 4 + hi) ^ lo) * 8)];
        s = __builtin_amdgcn_mfma_f32_16x16x32_bf16(qf[ds], kf, s, 0, 0, 0);
      }
      S[kb] = s;
    }
    __builtin_amdgcn_s_setprio(0);

    #pragma unroll
    for (int kb = 0; kb < 4; ++kb) {
      const int kidx = kt * 64 + kb * 16 + lo;
      #pragma unroll
      for (int j = 0; j < 4; ++j) {
        const float sv = S[kb][j] * scale;
        S[kb][j] = (mk[kb] != 0 && kidx <= qrow + hi * 4 + j) ? sv : NEG_INF;
      }
    }

    float p[4][4];
    #pragma unroll
    for (int j = 0; j < 4; ++j) {
      float tm = fmaxf(fmaxf(S[0][j], S[1][j]), fmaxf(S[2][j], S[3][j]));
      tm = fmaxf(tm, __shfl_xor(tm, 1, 64));
      tm = fmaxf(tm, __shfl_xor(tm, 2, 64));
      tm = fmaxf(tm, __shfl_xor(tm, 4, 64));
      tm = fmaxf(tm, __shfl_xor(tm, 8, 64));
      const float mn = fmaxf(mrow[j], tm);
      const float mn2 = (mn == NEG_INF) ? 0.f : mn;
      const float alpha = __expf(mrow[j] - mn2);
      float ps = 0.f;
      #pragma unroll
      for (int kb = 0; kb < 4; ++kb) { p[kb][j] = __expf(S[kb][j] - mn2); ps += p[kb][j]; }
      ps += __shfl_xor(ps, 1, 64);
      ps += __shfl_xor(ps, 2, 64);
      ps += __shfl_xor(ps, 4, 64);
      ps += __shfl_xor(ps, 8, 64);
      lrow[j] = lrow[j] * alpha + ps;
      mrow[j] = mn;
      #pragma unroll
      for (int n2 = 0; n2 < 8; ++n2) oacc[n2][j] *= alpha;
    }

    #pragma unroll
    for (int kb = 0; kb < 4; ++kb)
      #pragma unroll
      for (int j = 0; j < 4; ++j) {
        const int row = hi * 4 + j;
        Plds[w][row * 64 + ((((kb * 2 + (lo >> 3)) ^ (row & 7))) << 3) + (lo & 7)] = (bf16)p[kb][j];
      }

    __builtin_amdgcn_s_setprio(1);
    #pragma unroll
    for (int ks = 0; ks < 2; ++ks) {
      const bf16x8 pa = *(const bf16x8*)&Plds[w][lo * 64 + (((ks * 4 + hi) ^ s7) << 3)];
      #pragma unroll
      for (int n2 = 0; n2 < 8; ++n2) {
        const int r = n2 * 16 + lo;
        const bf16x8 vf = *(const bf16x8*)&Vt[buf][r * 64 + (((ks * 4 + hi) ^ s7) << 3)];
        oacc[n2] = __builtin_amdgcn_mfma_f32_16x16x32_bf16(pa, vf, oacc[n2], 0, 0, 0);
      }
    }
    __builtin_amdgcn_s_setprio(0);

    __syncthreads();
  }

  float inv[4];
  #pragma unroll
  for (int j = 0; j < 4; ++j) inv[j] = (lrow[j] > 0.f) ? 1.f / lrow[j] : 0.f;
  bf16* ob = O + (size_t)(b * L + qrow) * DM + h * 128;
  #pragma unroll
  for (int n2 = 0; n2 < 8; ++n2)
    #pragma unroll
    for (int j = 0; j < 4; ++j)
      ob[(size_t)(hi * 4 + j) * DM + n2 * 16 + lo] = (bf16)(oacc[n2][j] * inv[j]);
}

// ---------------------------------------------------------------------------
extern "C" void kernel_launch(void* const* d_in, const int* in_sizes, int n_in,
                              void* d_out, int out_size, void* d_ws, size_t ws_size,
                              hipStream_t stream)
{
  (void)in_sizes; (void)n_in; (void)out_size; (void)ws_size;
  const float* x        = (const float*)d_in[0];
  const float* rope_cos = (const float*)d_in[1];
  const float* rope_sin = (const float*)d_in[2];
  const int*   mask     = (const int*)d_in[3];
  const float* w_norm1  = (const float*)d_in[4];
  const float* w_norm2  = (const float*)d_in[5];
  const float* wq       = (const float*)d_in[6];
  const float* wk       = (const float*)d_in[7];
  const float* wv       = (const float*)d_in[8];
  const float* wo       = (const float*)d_in[9];
  const float* w_ff1    = (const float*)d_in[10];
  const float* w_ff2    = (const float*)d_in[11];
  float* out = (float*)d_out;

  const int M = 4096, D = 2048, FFD = 8192;
  char* ws = (char*)d_ws;
  const size_t WSLAB = 8388608ull;    // 2048*2048*2 B
  const size_t XNB   = 16777216ull;   // 4096*2048*2 B
  bf16* wqt  = (bf16*)(ws);           // wqt|wkt|wvt contiguous = [6144][2048]
  bf16* wkt  = (bf16*)(ws + WSLAB);
  bf16* wvt  = (bf16*)(ws + 2 * WSLAB);
  bf16* wot  = (bf16*)(ws + 3 * WSLAB);
  char* pool = ws + 4 * WSLAB;
  bf16* xn   = (bf16*)(pool);
  bf16* qb   = (bf16*)(pool + XNB);
  bf16* kb   = (bf16*)(pool + 2 * XNB);
  bf16* vb   = (bf16*)(pool + 3 * XNB);
  bf16* ao   = (bf16*)(pool + 4 * XNB);
  bf16* vt   = (bf16*)(pool);               // reuses xn after QKV GEMM
  bf16* kswz = (bf16*)(pool + 3 * XNB);     // reuses vb after v_transpose
  bf16* ff1t = (bf16*)(ws);                 // reuses wq_t..wo_t after WO GEMM
  bf16* hmid = (bf16*)(pool);               // reuses vt|qb|kb after attention
  bf16* ff2t = (bf16*)(ws);                 // reuses ff1_t after FF1
  bf16* xn2  = (bf16*)(pool + 4 * XNB);     // reuses ao after WO GEMM

  const dim3 tb(32, 8);

  rmsnorm_to_bf16<true><<<M, 256, 0, stream>>>(x, w_norm1, xn);
  transpose_to_bf16<true><<<dim3(D / 32, D / 32), tb, 0, stream>>>(wq, wqt, D, D);
  transpose_to_bf16<true><<<dim3(D / 32, D / 32), tb, 0, stream>>>(wk, wkt, D, D);
  transpose_to_bf16<true><<<dim3(D / 32, D / 32), tb, 0, stream>>>(wv, wvt, D, D);
  transpose_to_bf16<false><<<dim3(D / 32, D / 32), tb, 0, stream>>>(wo, wot, D, D);

  // fused QKV on the 256^2 pipeline: Bt = [6144][2048]
  gemm256<3><<<(M / 256) * (6144 / 256), 512, 0, stream>>>(xn, wqt, qb, M, 6144, D);

  // xn dead after QKV GEMM; vt overwrites it
  v_transpose<<<dim3(2048 / 32, 128 / 32, 32), tb, 0, stream>>>(vb, vt);

  // vb dead after v_transpose; kswz overwrites it
  rope_qk<<<2048, 256, 0, stream>>>(qb, kb, kswz, rope_cos, rope_sin);

  attn_fwd<<<1024, 256, 0, stream>>>(qb, kswz, vt, mask, ao);

  gemm_bt<1><<<(M / 128) * (D / 128), 256, 0, stream>>>(ao, wot, out, x, M, D, D);

  rmsnorm_to_bf16<true><<<M, 256, 0, stream>>>(out, w_norm2, xn2);

  transpose_to_bf16<true><<<dim3(FFD / 32, D / 32), tb, 0, stream>>>(w_ff1, ff1t, D, FFD);
  gemm256<2><<<(M / 256) * (FFD / 256), 512, 0, stream>>>(xn2, ff1t, hmid, M, FFD, D);

  transpose_to_bf16<false><<<dim3(D / 32, FFD / 32), tb, 0, stream>>>(w_ff2, ff2t, FFD, D);
  gemm_bt<1><<<(M / 128) * (D / 128), 256, 0, stream>>>(hmid, ff2t, out, out, M, D, FFD);
}